// Round 3
// baseline (153.814 us; speedup 1.0000x reference)
//
#include <hip/hip_runtime.h>

// VQ-VAE eval forward, MFMA bf16x3-split path, R3:
//  - bf16x3 code planes precomputed ONCE in vq_prep -> ws (frag-ready tiles)
//  - vq_main stages tiles via global_load_lds width-16 DMA (no VALU split,
//    no bank conflicts), double-buffered
//  - vq_final fused into vq_main via last-block pattern (device-scope atomics)

#define DIMS 64
#define K_CODES 1024
#define NQ 65536
#define HW 1024
#define TOT 4194304
#define PLANE 4096                 // shorts per plane per 64-code tile
#define TILE_BYTES 24576           // 3 planes * 4096 shorts * 2B

// ws layout (bytes)
#define WS_NORM   0        // float[1024]
#define WS_FLAGS  4096     // int[1024]
#define WS_LOSS   8192     // float
#define WS_CNT    8256     // int
#define WS_PLANES 16384    // ushort[16][3][8][64][8]  (384 KB)

typedef __attribute__((ext_vector_type(8))) short v8s;
typedef __attribute__((ext_vector_type(4))) float f32x4;

__device__ inline unsigned short f2bf(float x) {
    union { float f; unsigned u; } v; v.f = x;
    unsigned r = v.u + 0x7fff + ((v.u >> 16) & 1);  // RNE
    return (unsigned short)(r >> 16);
}
__device__ inline float bf2f(unsigned short h) {
    union { unsigned u; float f; } v; v.u = ((unsigned)h) << 16; return v.f;
}
__device__ inline void cp16(void* lds, const void* g) {
    __builtin_amdgcn_global_load_lds(
        (const __attribute__((address_space(1))) void*)g,
        (__attribute__((address_space(3))) void*)lds, 16, 0, 0);
}

#define MFMA16(A_, B_, C_) __builtin_amdgcn_mfma_f32_16x16x32_bf16(A_, B_, C_, 0, 0, 0)

// ---------------- Kernel A: split planes + norms + zero accumulators ----------------
// 16 blocks x 256 threads.
__global__ void vq_prep(const float* __restrict__ emb, char* __restrict__ ws) {
    float* norms = (float*)(ws + WS_NORM);
    int*   flags = (int*)(ws + WS_FLAGS);
    unsigned short* planes = (unsigned short*)(ws + WS_PLANES);

    const int tid = threadIdx.x;
    const float4* src = (const float4*)emb;
#pragma unroll
    for (int i = 0; i < 4; ++i) {
        int f4 = blockIdx.x * 1024 + i * 256 + tid;  // 0..16383, lanes contiguous
        int code = f4 >> 4;
        int t    = code >> 6;
        int c    = code & 63;
        int o    = (f4 >> 1) & 7;
        int sub  = (f4 & 1) * 4;
        float4 v = src[f4];
        float xs[4] = {v.x, v.y, v.z, v.w};
        unsigned short h[4], m[4], l[4];
#pragma unroll
        for (int q = 0; q < 4; ++q) {
            float x = xs[q];
            unsigned short hh = f2bf(x);  float r1 = x - bf2f(hh);
            unsigned short mh = f2bf(r1); float r2 = r1 - bf2f(mh);
            h[q] = hh; m[q] = mh; l[q] = f2bf(r2);
        }
        unsigned short* base = planes + (size_t)t * 12288 + ((o * 64 + c) * 8 + sub);
        uint2 uh, um, ul;
        uh.x = (unsigned)h[0] | ((unsigned)h[1] << 16);
        uh.y = (unsigned)h[2] | ((unsigned)h[3] << 16);
        um.x = (unsigned)m[0] | ((unsigned)m[1] << 16);
        um.y = (unsigned)m[2] | ((unsigned)m[3] << 16);
        ul.x = (unsigned)l[0] | ((unsigned)l[1] << 16);
        ul.y = (unsigned)l[2] | ((unsigned)l[3] << 16);
        *(uint2*)(base)             = uh;
        *(uint2*)(base + PLANE)     = um;
        *(uint2*)(base + 2 * PLANE) = ul;
    }
    int g = blockIdx.x * 256 + tid;
    if (g < K_CODES) {
        const float4* row = (const float4*)(emb + g * DIMS);
        float s = 0.f;
#pragma unroll
        for (int i = 0; i < 16; ++i) {
            float4 v = row[i];
            s += v.x * v.x + v.y * v.y + v.z * v.z + v.w * v.w;
        }
        norms[g] = s;
        flags[g] = 0;
    }
    if (g == 0) { *(float*)(ws + WS_LOSS) = 0.f; *(int*)(ws + WS_CNT) = 0; }
}

// ---------------- Kernel B: MFMA distances + argmin + gather + loss + final ----------------
// 512 blocks x 256 threads (4 waves). Block = 128 queries; wave = 32 queries.
__global__ __launch_bounds__(256, 2)
void vq_main(const float* __restrict__ z_e, const float* __restrict__ emb,
             char* __restrict__ ws, float* __restrict__ out) {
    __shared__ unsigned short ldsB[2][3 * PLANE];  // 48 KB double buffer
    __shared__ int   fIdx[128];
    __shared__ float wsum[4];
    __shared__ int   amLast;

    const float* norms = (const float*)(ws + WS_NORM);
    int*   flags   = (int*)(ws + WS_FLAGS);
    float* ws_loss = (float*)(ws + WS_LOSS);
    int*   ws_cnt  = (int*)(ws + WS_CNT);
    const char* planes = (const char*)(ws + WS_PLANES);

    const int tid  = threadIdx.x;
    const int lane = tid & 63;
    const int wid  = tid >> 6;
    const int qbase = blockIdx.x * 128;
    const int b    = qbase >> 10;
    const int hwb  = qbase & (HW - 1);
    const int col  = lane & 15;
    const int qd   = lane >> 4;

    // ---- A fragments: split queries into 3 bf16 planes (registers) ----
    v8s afr[2][2][3];
    {
        const float* zb = z_e + b * (DIMS * HW);
#pragma unroll
        for (int rt = 0; rt < 2; ++rt) {
            int hwq = hwb + wid * 32 + rt * 16 + col;
#pragma unroll
            for (int kc = 0; kc < 2; ++kc) {
                int dbase = kc * 32 + qd * 8;
#pragma unroll
                for (int j = 0; j < 8; ++j) {
                    float x = zb[(dbase + j) * HW + hwq];
                    unsigned short h = f2bf(x);  float r1 = x - bf2f(h);
                    unsigned short m = f2bf(r1); float r2 = r1 - bf2f(m);
                    afr[rt][kc][0][j] = (short)h;
                    afr[rt][kc][1][j] = (short)m;
                    afr[rt][kc][2][j] = (short)f2bf(r2);
                }
            }
        }
    }

    float bestv[2][4];
    int   besti[2][4];
#pragma unroll
    for (int rt = 0; rt < 2; ++rt)
#pragma unroll
        for (int r = 0; r < 4; ++r) { bestv[rt][r] = 3.4e38f; besti[rt][r] = 0; }

    // Stage tile t into buffer buf: straight 24 KB DMA, wave w copies bytes
    // [w*6144, w*6144+6144) as 6 chunks of 1024 B (lane-contiguous, conflict-free).
    auto stage = [&](int t, int buf) {
        const char* g = planes + (size_t)t * TILE_BYTES + wid * 6144 + lane * 16;
        char* l = ((char*)&ldsB[buf][0]) + wid * 6144;
#pragma unroll
        for (int c = 0; c < 6; ++c)
            cp16(l + c * 1024, g + c * 1024);
    };

    stage(0, 0);
    __syncthreads();

    for (int t = 0; t < 16; ++t) {
        const int cur = t & 1;
        if (t < 15) stage(t + 1, 1 - cur);  // async, lands during MFMA phase
        const unsigned short* bufc = &ldsB[cur][0];
#pragma unroll
        for (int cs = 0; cs < 4; ++cs) {
            float nrm = norms[t * 64 + cs * 16 + col];
            v8s bfr[2][3];
#pragma unroll
            for (int kc = 0; kc < 2; ++kc)
#pragma unroll
                for (int p = 0; p < 3; ++p)
                    bfr[kc][p] = *(const v8s*)(bufc + p * PLANE +
                                 (((kc * 4 + qd) * 64) + cs * 16 + col) * 8);
            f32x4 acc0 = {0.f, 0.f, 0.f, 0.f};
            f32x4 acc1 = {0.f, 0.f, 0.f, 0.f};
#pragma unroll
            for (int kc = 0; kc < 2; ++kc) {
                acc0 = MFMA16(afr[0][kc][0], bfr[kc][0], acc0);  // hh
                acc1 = MFMA16(afr[1][kc][0], bfr[kc][0], acc1);
                acc0 = MFMA16(afr[0][kc][0], bfr[kc][1], acc0);  // hm
                acc1 = MFMA16(afr[1][kc][0], bfr[kc][1], acc1);
                acc0 = MFMA16(afr[0][kc][1], bfr[kc][0], acc0);  // mh
                acc1 = MFMA16(afr[1][kc][1], bfr[kc][0], acc1);
                acc0 = MFMA16(afr[0][kc][1], bfr[kc][1], acc0);  // mm
                acc1 = MFMA16(afr[1][kc][1], bfr[kc][1], acc1);
                acc0 = MFMA16(afr[0][kc][0], bfr[kc][2], acc0);  // hl
                acc1 = MFMA16(afr[1][kc][0], bfr[kc][2], acc1);
                acc0 = MFMA16(afr[0][kc][2], bfr[kc][0], acc0);  // lh
                acc1 = MFMA16(afr[1][kc][2], bfr[kc][0], acc1);
            }
            int cbase = t * 64 + cs * 16 + col;
#pragma unroll
            for (int r = 0; r < 4; ++r) {
                float d0 = fmaf(-2.f, acc0[r], nrm);
                if (d0 < bestv[0][r]) { bestv[0][r] = d0; besti[0][r] = cbase; }
                float d1 = fmaf(-2.f, acc1[r], nrm);
                if (d1 < bestv[1][r]) { bestv[1][r] = d1; besti[1][r] = cbase; }
            }
        }
        __syncthreads();  // drains lgkm + vmcnt: next buffer complete
    }

    // ---- argmin across the 16 columns (C/D: row=qd*4+r, col=lane&15) ----
#pragma unroll
    for (int rt = 0; rt < 2; ++rt)
#pragma unroll
    for (int r = 0; r < 4; ++r) {
        float v = bestv[rt][r];
        int   idx = besti[rt][r];
#pragma unroll
        for (int m = 8; m >= 1; m >>= 1) {
            float ov = __shfl_xor(v, m, 64);
            int   oi = __shfl_xor(idx, m, 64);
            if (ov < v || (ov == v && oi < idx)) { v = ov; idx = oi; }
        }
        if (col == 0) {
            int q = wid * 32 + rt * 16 + qd * 4 + r;
            fIdx[q] = idx;
            out[TOT + 1 + qbase + q] = (float)idx;
            atomicExch(&flags[idx], 1);  // device-scope
        }
    }
    __syncthreads();

    // ---- gather z_q, coalesced write, mse partial ----
    const int q  = tid & 127;
    const int dh = tid >> 7;
    const int n  = qbase + q;
    const int bb = n >> 10;
    const int hw = n & (HW - 1);
    const int myIdx = fIdx[q];
    const float* erow = emb + myIdx * DIMS;
    float lsum = 0.f;
#pragma unroll
    for (int it = 0; it < 32; ++it) {
        int d = it * 2 + dh;
        float v = erow[d];
        int   o = bb * (DIMS * HW) + d * HW + hw;
        float ze = z_e[o];
        out[o] = v;
        float df = ze - v;
        lsum = fmaf(df, df, lsum);
    }
#pragma unroll
    for (int off = 32; off > 0; off >>= 1) lsum += __shfl_down(lsum, off, 64);
    if (lane == 0) wsum[wid] = lsum;
    __syncthreads();
    if (tid == 0) {
        atomicAdd(ws_loss, wsum[0] + wsum[1] + wsum[2] + wsum[3]);
        __threadfence();
        int prev = atomicAdd(ws_cnt, 1);
        amLast = (prev == (int)gridDim.x - 1);
    }
    __syncthreads();

    // ---- last block: finalize usage + loss ----
    if (amLast) {
        __threadfence();
        float c = 0.f;
#pragma unroll
        for (int i = 0; i < 4; ++i)
            c += (float)atomicAdd(&flags[tid + 256 * i], 0);  // device-scope read
#pragma unroll
        for (int off = 32; off > 0; off >>= 1) c += __shfl_down(c, off, 64);
        if (lane == 0) wsum[wid] = c;
        __syncthreads();
        if (tid == 0) {
            float used = wsum[0] + wsum[1] + wsum[2] + wsum[3];
            out[TOT + 1 + NQ] = used / (float)K_CODES;
            float L = atomicAdd(ws_loss, 0.f);
            out[TOT] = L / (float)TOT;
        }
    }
}

extern "C" void kernel_launch(void* const* d_in, const int* in_sizes, int n_in,
                              void* d_out, int out_size, void* d_ws, size_t ws_size,
                              hipStream_t stream) {
    const float* z_e = (const float*)d_in[0];
    const float* emb = (const float*)d_in[1];
    float* out = (float*)d_out;
    char* ws = (char*)d_ws;

    vq_prep<<<16, 256, 0, stream>>>(emb, ws);
    vq_main<<<512, 256, 0, stream>>>(z_e, emb, ws, out);
}